// Round 6
// baseline (242.904 us; speedup 1.0000x reference)
//
#include <hip/hip_runtime.h>

#define NB_ 32
#define NP_ 65536
#define NT_ 16
#define HB 1024
#define HSCALE 128.0f
#define NBX 16     // kernel1 blocks per batch
#define CHUNKS 4   // 1024-prior chunks per block (4096 priors/block)

__device__ __forceinline__ float softplus_(float x) {
    // log(1 + e^x), stable
    return fmaxf(x, 0.0f) + __logf(1.0f + __expf(-fabsf(x)));
}

__device__ __forceinline__ float iou_fast(float tx0, float ty0, float tx1, float ty1, float ta,
                                          float bx0, float by0, float bx1, float by1, float ar) {
    float lx = fmaxf(tx0, bx0), ly = fmaxf(ty0, by0);
    float rx = fminf(tx1, bx1), ry = fminf(ty1, by1);
    float w = fmaxf(rx - lx, 0.0f), h = fmaxf(ry - ly, 0.0f);
    float inter = w * h;
    return __fdividef(inter, ta + ar - inter);
}

// Kernel 1: fused match + losses + per-block histogram. All outputs are
// deterministic per-block stores (no atomics into ws -> no memset needed).
__global__ void __launch_bounds__(256, 4) mainK(
    const float* __restrict__ loc, const float* __restrict__ conf,
    const float* __restrict__ priors, const float* __restrict__ targets,
    int* __restrict__ gcnt, float* __restrict__ gsum,
    unsigned long long* __restrict__ bestPart,
    float* __restrict__ part_ll, float* __restrict__ part_pc, int* __restrict__ part_np,
    unsigned* __restrict__ ticket)
{
    const int bx = blockIdx.x, b = blockIdx.y, tid = threadIdx.x;

    __shared__ float tr[NT_][5];  // x0,y0,x1,y1,area
    __shared__ int hc[HB];
    __shared__ float hs[HB];
    __shared__ unsigned wkey[4][NT_], wp[4][NT_];
    __shared__ float sh_ll[4], sh_pc[4];
    __shared__ int sh_np[4];

    if (b == 0 && bx == 0 && tid == 0) *ticket = 0u;  // init for kernel2 (stream-ordered)

    for (int i = tid; i < HB; i += 256) { hc[i] = 0; hs[i] = 0.0f; }
    if (tid < NT_) {
        const float* tp = targets + ((size_t)b * NT_ + tid) * 5;
        float x0 = tp[0], y0 = tp[1], x1 = tp[2], y1 = tp[3];
        tr[tid][0] = x0; tr[tid][1] = y0; tr[tid][2] = x1; tr[tid][3] = y1;
        tr[tid][4] = (x1 - x0) * (y1 - y0);
    }
    __syncthreads();

    float ll_acc = 0.0f, pc_acc = 0.0f;
    int np_acc = 0;
    unsigned tkey[NT_];   // per-truth best (iou_key | (15-ci)) over this thread's priors
#pragma unroll
    for (int t = 0; t < NT_; t++) tkey[t] = 0u;

    for (int c = 0; c < CHUNKS; c++) {
        const int pbase = (bx * CHUNKS + c) * 1024 + tid;
        float4 pr[4];
        float pbx0[4], pby0[4], pbx1[4], pby1[4], par[4];
#pragma unroll
        for (int i = 0; i < 4; i++) {
            pr[i] = ((const float4*)priors)[pbase + 256 * i];
            float hw = pr[i].z * 0.5f, hh = pr[i].w * 0.5f;
            pbx0[i] = pr[i].x - hw; pby0[i] = pr[i].y - hh;
            pbx1[i] = pr[i].x + hw; pby1[i] = pr[i].y + hh;
            par[i] = (pbx1[i] - pbx0[i]) * (pby1[i] - pby0[i]);
        }
        unsigned pkey[4] = {0u, 0u, 0u, 0u};  // per-prior best (iou_key | (15-t))
#pragma unroll
        for (int t = 0; t < NT_; t++) {
            float tx0 = tr[t][0], ty0 = tr[t][1], tx1 = tr[t][2], ty1 = tr[t][3], ta = tr[t][4];
            unsigned lowt = (unsigned)(15 - t);
            unsigned lowc = (unsigned)(15 - c * 4);
#pragma unroll
            for (int i = 0; i < 4; i++) {
                float iou = iou_fast(tx0, ty0, tx1, ty1, ta,
                                     pbx0[i], pby0[i], pbx1[i], pby1[i], par[i]);
                // monotone u32 key; 2 LSB mantissa bits -> 4-bit tie-break index
                // (ties prefer smaller t / smaller prior index)
                unsigned base = (__float_as_uint(iou) & 0xFFFFFFFCu) << 2;
                unsigned kt = base | lowt;
                unsigned kp = base | (lowc - (unsigned)i);
                pkey[i] = (kt > pkey[i]) ? kt : pkey[i];
                tkey[t] = (kp > tkey[t]) ? kp : tkey[t];
            }
        }
#pragma unroll
        for (int i = 0; i < 4; i++) {
            int p = pbase + 256 * i;
            size_t bp = (size_t)b * NP_ + p;
            bool pos = (pkey[i] >= 0xFC000000u);  // iou >= 0.5 (0.5 has zero low bits)
            float2 cxy = ((const float2*)conf)[bp];
            float dd = cxy.y - cxy.x;
            float v = pos ? 0.0f : softplus_(dd);  // loss_c_mine
            int bin = min(HB - 1, (int)(v * HSCALE));
            atomicAdd(&hc[bin], 1);
            atomicAdd(&hs[bin], v);
            if (pos) {
                np_acc++;
                pc_acc += softplus_(-dd);  // lse - c.y
                int t = 15 - (int)(pkey[i] & 15u);
                float tx0 = tr[t][0], ty0 = tr[t][1], tx1 = tr[t][2], ty1 = tr[t][3];
                float gcx = ((tx0 + tx1) * 0.5f - pr[i].x) / (0.1f * pr[i].z);
                float gcy = ((ty0 + ty1) * 0.5f - pr[i].y) / (0.1f * pr[i].w);
                float gw = __logf((tx1 - tx0) / pr[i].z) * 5.0f;
                float gh = __logf((ty1 - ty0) / pr[i].w) * 5.0f;
                float4 ld = ((const float4*)loc)[bp];
                float d0 = fabsf(ld.x - gcx), d1 = fabsf(ld.y - gcy);
                float d2 = fabsf(ld.z - gw),  d3 = fabsf(ld.w - gh);
                ll_acc += (d0 < 1.0f) ? 0.5f * d0 * d0 : d0 - 0.5f;
                ll_acc += (d1 < 1.0f) ? 0.5f * d1 * d1 : d1 - 0.5f;
                ll_acc += (d2 < 1.0f) ? 0.5f * d2 * d2 : d2 - 0.5f;
                ll_acc += (d3 < 1.0f) ? 0.5f * d3 * d3 : d3 - 0.5f;
            }
        }
    }

    // per-wave reductions
    const int wave = tid >> 6, lane = tid & 63;
#pragma unroll
    for (int t = 0; t < NT_; t++) {
        unsigned k = tkey[t], m = k;
        for (int off = 32; off > 0; off >>= 1) {
            unsigned o = __shfl_down(m, off, 64);
            m = (o > m) ? o : m;
        }
        m = __shfl(m, 0, 64);
        unsigned long long ball = __ballot(k == m);
        if (lane == 0) {
            int l = __ffsll((long long)ball) - 1;  // lowest lane = smallest p (same ci)
            int ci = 15 - (int)(m & 15u);
            int p = bx * (CHUNKS * 1024) + ci * 256 + wave * 64 + l;
            wkey[wave][t] = m;
            wp[wave][t] = (unsigned)p;
        }
    }
    for (int off = 32; off > 0; off >>= 1) {
        ll_acc += __shfl_down(ll_acc, off, 64);
        pc_acc += __shfl_down(pc_acc, off, 64);
        np_acc += __shfl_down(np_acc, off, 64);
    }
    if (lane == 0) { sh_ll[wave] = ll_acc; sh_pc[wave] = pc_acc; sh_np[wave] = np_acc; }
    __syncthreads();

    if (tid < NT_) {
        unsigned bk = wkey[0][tid], bpv = wp[0][tid];
        for (int w = 1; w < 4; w++) {
            unsigned k2 = wkey[w][tid], p2 = wp[w][tid];
            if (k2 > bk || (k2 == bk && p2 < bpv)) { bk = k2; bpv = p2; }
        }
        unsigned long long pk = (((unsigned long long)bk) << 32) | (unsigned)(~bpv);
        bestPart[((size_t)b * NT_ + tid) * NBX + bx] = pk;   // plain store
    }
    if (tid == 0) {
        part_ll[b * NBX + bx] = sh_ll[0] + sh_ll[1] + sh_ll[2] + sh_ll[3];
        part_pc[b * NBX + bx] = sh_pc[0] + sh_pc[1] + sh_pc[2] + sh_pc[3];
        part_np[b * NBX + bx] = sh_np[0] + sh_np[1] + sh_np[2] + sh_np[3];
    }
    // deterministic per-block hist writeback (coalesced)
    int* gc = gcnt + ((size_t)(b * NBX + bx)) * HB;
    float* gs = gsum + ((size_t)(b * NBX + bx)) * HB;
    for (int i = tid; i < HB; i += 256) { gc[i] = hc[i]; gs[i] = hs[i]; }
}

// Kernel 2: per-batch merge + fixup + selection; last block does final reduce.
__global__ void __launch_bounds__(256) finishK(
    const float* __restrict__ loc, const float* __restrict__ conf,
    const float* __restrict__ priors, const float* __restrict__ targets,
    const int* __restrict__ gcnt, const float* __restrict__ gsum,
    const unsigned long long* __restrict__ bestPart,
    const float* __restrict__ part_ll, const float* __restrict__ part_pc,
    const int* __restrict__ part_np,
    float* __restrict__ final_l, float* __restrict__ final_c, int* __restrict__ final_n,
    unsigned* __restrict__ ticket, float* __restrict__ out)
{
    const int b = blockIdx.x, tid = threadIdx.x;
    __shared__ int hc[HB];
    __shared__ float hs[HB];
    __shared__ float tr[NT_][5];
    __shared__ unsigned ps[NT_];
    __shared__ float s_dll, s_dpc;
    __shared__ int s_dnp;
    __shared__ unsigned ccnt[16];
    __shared__ float csm[16];
    __shared__ int s_last;

    if (tid == 0) { s_dll = 0.0f; s_dpc = 0.0f; s_dnp = 0; s_last = 0; }
    if (tid < NT_) {
        const float* tp = targets + ((size_t)b * NT_ + tid) * 5;
        float x0 = tp[0], y0 = tp[1], x1 = tp[2], y1 = tp[3];
        tr[tid][0] = x0; tr[tid][1] = y0; tr[tid][2] = x1; tr[tid][3] = y1;
        tr[tid][4] = (x1 - x0) * (y1 - y0);
    }
    // merge 16 per-block hists (coalesced over bins)
    for (int i = tid; i < HB; i += 256) {
        int c = 0; float s = 0.0f;
        for (int j = 0; j < NBX; j++) {
            c += gcnt[((size_t)(b * NBX + j)) * HB + i];
            s += gsum[((size_t)(b * NBX + j)) * HB + i];
        }
        hc[i] = c; hs[i] = s;
    }
    // merge per-truth best priors
    if (tid < NT_) {
        unsigned long long v = bestPart[((size_t)b * NT_ + tid) * NBX];
        for (int j = 1; j < NBX; j++) {
            unsigned long long u = bestPart[((size_t)b * NT_ + tid) * NBX + j];
            if (u > v) v = u;   // equal keys keep first j = smaller prior range
        }
        ps[tid] = ~((unsigned)(v & 0xffffffffULL));
    }
    __syncthreads();

    // fixup (16 threads), adjustments into LDS
    if (tid < NT_) {
        unsigned p = ps[tid];
        bool active = true;
        for (int u = tid + 1; u < NT_; u++)
            if (ps[u] == p) { active = false; break; }  // last-wins dedup
        if (active) {
            float4 prv = ((const float4*)priors)[p];
            float hw = prv.z * 0.5f, hh = prv.w * 0.5f;
            float qx0 = prv.x - hw, qy0 = prv.y - hh;
            float qx1 = prv.x + hw, qy1 = prv.y + hh;
            float areab = (qx1 - qx0) * (qy1 - qy0);
            unsigned pk = 0u;
            for (int tt = 0; tt < NT_; tt++) {
                float iou = iou_fast(tr[tt][0], tr[tt][1], tr[tt][2], tr[tt][3], tr[tt][4],
                                     qx0, qy0, qx1, qy1, areab);
                unsigned cand = ((__float_as_uint(iou) & 0xFFFFFFFCu) << 2)
                              | (unsigned)(15 - tt);
                pk = (cand > pk) ? cand : pk;
            }
            bool pos0 = (pk >= 0xFC000000u);   // identical rule to kernel1
            int t0 = 15 - (int)(pk & 15u);
            size_t bp = (size_t)b * NP_ + p;
            float2 cxy = ((const float2*)conf)[bp];
            float dd = cxy.y - cxy.x;
            float4 ld = ((const float4*)loc)[bp];

            auto sl1_of = [&](int tt) -> float {
                float tx0 = tr[tt][0], ty0 = tr[tt][1], tx1 = tr[tt][2], ty1 = tr[tt][3];
                float gcx = ((tx0 + tx1) * 0.5f - prv.x) / (0.1f * prv.z);
                float gcy = ((ty0 + ty1) * 0.5f - prv.y) / (0.1f * prv.w);
                float gw = __logf((tx1 - tx0) / prv.z) * 5.0f;
                float gh = __logf((ty1 - ty0) / prv.w) * 5.0f;
                float d0 = fabsf(ld.x - gcx), d1 = fabsf(ld.y - gcy);
                float d2 = fabsf(ld.z - gw),  d3 = fabsf(ld.w - gh);
                float s = (d0 < 1.0f) ? 0.5f * d0 * d0 : d0 - 0.5f;
                s += (d1 < 1.0f) ? 0.5f * d1 * d1 : d1 - 0.5f;
                s += (d2 < 1.0f) ? 0.5f * d2 * d2 : d2 - 0.5f;
                s += (d3 < 1.0f) ? 0.5f * d3 * d3 : d3 - 0.5f;
                return s;
            };
            float dll = sl1_of(tid) - (pos0 ? sl1_of(t0) : 0.0f);
            atomicAdd(&s_dll, dll);
            if (!pos0) {
                float v = softplus_(dd);  // identical expr to kernel1's binned value
                int bin = min(HB - 1, (int)(v * HSCALE));
                atomicSub(&hc[bin], 1);
                atomicAdd(&hs[bin], -v);
                atomicAdd(&s_dpc, softplus_(-dd));
                atomicAdd(&s_dnp, 1);
            }
        }
    }
    __syncthreads();

    if (tid < 16) {
        unsigned cacc = 0; float sacc = 0.0f;
        for (int j = 0; j < 64; j++) { cacc += (unsigned)hc[tid * 64 + j]; sacc += hs[tid * 64 + j]; }
        ccnt[tid] = cacc; csm[tid] = sacc;
    }
    __syncthreads();

    if (tid == 0) {
        float sll = s_dll, spc = s_dpc;
        int n = s_dnp;
        for (int j = 0; j < NBX; j++) {
            sll += part_ll[b * NBX + j];
            spc += part_pc[b * NBX + j];
            n += part_np[b * NBX + j];
        }
        int K = 3 * n;
        if (K > NP_ - 1) K = NP_ - 1;
        float tk = 0.0f;
        if (K > 0) {
            unsigned need = (unsigned)K, cum = 0;
            float s = 0.0f;
            int cb = 15;
            for (; cb > 0; --cb) {
                if (cum + ccnt[cb] >= need) break;
                cum += ccnt[cb]; s += csm[cb];
            }
            int bin = cb * 64 + 63;
            for (; bin > cb * 64; --bin) {
                if (cum + (unsigned)hc[bin] >= need) break;
                cum += (unsigned)hc[bin]; s += hs[bin];
            }
            unsigned rem = need - cum;
            int cv = hc[bin];
            float avg = (cv > 0) ? __fdividef(hs[bin], (float)cv) : 0.0f;
            tk = s + (float)rem * avg;
        }
        final_l[b] = sll;
        final_c[b] = spc + tk;
        final_n[b] = n;
        __threadfence();
        unsigned old = atomicAdd(ticket, 1u);
        if (old == NB_ - 1) s_last = 1;
    }
    __syncthreads();

    if (s_last) {
        __threadfence();  // acquire: see all other blocks' final_* stores
        if (tid < 64) {
            float lv = 0.0f, cv = 0.0f;
            int nv = 0;
            if (tid < NB_) { lv = final_l[tid]; cv = final_c[tid]; nv = final_n[tid]; }
            for (int off = 32; off > 0; off >>= 1) {
                lv += __shfl_down(lv, off, 64);
                cv += __shfl_down(cv, off, 64);
                nv += __shfl_down(nv, off, 64);
            }
            if (tid == 0) {
                float fn = (float)nv;
                out[0] = lv / fn;
                out[1] = cv / fn;
            }
        }
    }
}

extern "C" void kernel_launch(void* const* d_in, const int* in_sizes, int n_in,
                              void* d_out, int out_size, void* d_ws, size_t ws_size,
                              hipStream_t stream) {
    const float* loc = (const float*)d_in[0];
    const float* conf = (const float*)d_in[1];
    const float* priors = (const float*)d_in[2];
    const float* targets = (const float*)d_in[3];
    float* out = (float*)d_out;

    char* w = (char*)d_ws;
    int* gcnt = (int*)w;                                   // 512*1024*4 = 2 MB
    float* gsum = (float*)(w + (2u << 20));                // 2 MB
    char* acc = w + (4u << 20);
    unsigned long long* bestPart = (unsigned long long*)acc;        // 32*16*16*8 = 64 KB
    float* part_ll = (float*)(acc + 65536);                         // 2 KB
    float* part_pc = (float*)(acc + 65536 + 2048);                  // 2 KB
    int* part_np   = (int*)(acc + 65536 + 4096);                    // 2 KB
    float* final_l = (float*)(acc + 65536 + 6144);                  // 128 B
    float* final_c = (float*)(acc + 65536 + 6272);
    int* final_n   = (int*)(acc + 65536 + 6400);
    unsigned* ticket = (unsigned*)(acc + 65536 + 6528);

    mainK<<<dim3(NBX, NB_), 256, 0, stream>>>(loc, conf, priors, targets,
                                              gcnt, gsum, bestPart,
                                              part_ll, part_pc, part_np, ticket);
    finishK<<<NB_, 256, 0, stream>>>(loc, conf, priors, targets, gcnt, gsum, bestPart,
                                     part_ll, part_pc, part_np,
                                     final_l, final_c, final_n, ticket, out);
}

// Round 7
// 149.258 us; speedup vs baseline: 1.6274x; 1.6274x over previous
//
#include <hip/hip_runtime.h>

#define NB_ 32
#define NP_ 65536
#define NT_ 16
#define HB 1024
#define HSCALE 128.0f
#define NBX 32     // kernel1 blocks per batch
#define CHUNKS 2   // 1024-prior chunks per block (2048 priors/block)

__device__ __forceinline__ float softplus_(float x) {
    // log(1 + e^x), stable
    return fmaxf(x, 0.0f) + __logf(1.0f + __expf(-fabsf(x)));
}

__device__ __forceinline__ float iou_fast(float tx0, float ty0, float tx1, float ty1, float ta,
                                          float bx0, float by0, float bx1, float by1, float ar) {
    float lx = fmaxf(tx0, bx0), ly = fmaxf(ty0, by0);
    float rx = fminf(tx1, bx1), ry = fminf(ty1, by1);
    float w = fmaxf(rx - lx, 0.0f), h = fmaxf(ry - ly, 0.0f);
    float inter = w * h;
    return __fdividef(inter, ta + ar - inter);
}

// Kernel 1: fused match + losses + per-block histogram. Deterministic stores
// only (no ws atomics -> no memset node). NOTE: no min-waves launch_bounds —
// R6 showed (256,4) caps VGPR at 64 and spills ~250 MB of scratch traffic.
__global__ void __launch_bounds__(256) mainK(
    const float* __restrict__ loc, const float* __restrict__ conf,
    const float* __restrict__ priors, const float* __restrict__ targets,
    int* __restrict__ gcnt, float* __restrict__ gsum,
    unsigned long long* __restrict__ bestPart,
    float* __restrict__ part_ll, float* __restrict__ part_pc, int* __restrict__ part_np,
    unsigned* __restrict__ ticket)
{
    const int bx = blockIdx.x, b = blockIdx.y, tid = threadIdx.x;

    __shared__ float tr[NT_][5];  // x0,y0,x1,y1,area
    __shared__ int hc[HB];
    __shared__ float hs[HB];
    __shared__ unsigned wkey[4][NT_], wp[4][NT_];
    __shared__ float sh_ll[4], sh_pc[4];
    __shared__ int sh_np[4];

    if (b == 0 && bx == 0 && tid == 0) *ticket = 0u;  // init for kernel2 (stream-ordered)

    for (int i = tid; i < HB; i += 256) { hc[i] = 0; hs[i] = 0.0f; }
    if (tid < NT_) {
        const float* tp = targets + ((size_t)b * NT_ + tid) * 5;
        float x0 = tp[0], y0 = tp[1], x1 = tp[2], y1 = tp[3];
        tr[tid][0] = x0; tr[tid][1] = y0; tr[tid][2] = x1; tr[tid][3] = y1;
        tr[tid][4] = (x1 - x0) * (y1 - y0);
    }
    __syncthreads();

    float ll_acc = 0.0f, pc_acc = 0.0f;
    int np_acc = 0;
    unsigned tkey[NT_];   // per-truth best (iou_key | (15-ci)) over this thread's priors
#pragma unroll
    for (int t = 0; t < NT_; t++) tkey[t] = 0u;

    for (int c = 0; c < CHUNKS; c++) {
        const int pbase = (bx * CHUNKS + c) * 1024 + tid;
        float4 pr[4];
        float pbx0[4], pby0[4], pbx1[4], pby1[4], par[4];
#pragma unroll
        for (int i = 0; i < 4; i++) {
            pr[i] = ((const float4*)priors)[pbase + 256 * i];
            float hw = pr[i].z * 0.5f, hh = pr[i].w * 0.5f;
            pbx0[i] = pr[i].x - hw; pby0[i] = pr[i].y - hh;
            pbx1[i] = pr[i].x + hw; pby1[i] = pr[i].y + hh;
            par[i] = (pbx1[i] - pbx0[i]) * (pby1[i] - pby0[i]);
        }
        unsigned pkey[4] = {0u, 0u, 0u, 0u};  // per-prior best (iou_key | (15-t))
#pragma unroll
        for (int t = 0; t < NT_; t++) {
            float tx0 = tr[t][0], ty0 = tr[t][1], tx1 = tr[t][2], ty1 = tr[t][3], ta = tr[t][4];
            unsigned lowt = (unsigned)(15 - t);
            unsigned lowc = (unsigned)(15 - c * 4);
#pragma unroll
            for (int i = 0; i < 4; i++) {
                float iou = iou_fast(tx0, ty0, tx1, ty1, ta,
                                     pbx0[i], pby0[i], pbx1[i], pby1[i], par[i]);
                // monotone u32 key; 2 LSB mantissa bits -> 4-bit tie-break index
                // (ties prefer smaller t / smaller prior index)
                unsigned base = (__float_as_uint(iou) & 0xFFFFFFFCu) << 2;
                unsigned kt = base | lowt;
                unsigned kp = base | (lowc - (unsigned)i);
                pkey[i] = (kt > pkey[i]) ? kt : pkey[i];
                tkey[t] = (kp > tkey[t]) ? kp : tkey[t];
            }
        }
#pragma unroll
        for (int i = 0; i < 4; i++) {
            int p = pbase + 256 * i;
            size_t bp = (size_t)b * NP_ + p;
            bool pos = (pkey[i] >= 0xFC000000u);  // iou >= 0.5 (0.5 has zero low bits)
            float2 cxy = ((const float2*)conf)[bp];
            float dd = cxy.y - cxy.x;
            float v = pos ? 0.0f : softplus_(dd);  // loss_c_mine
            int bin = min(HB - 1, (int)(v * HSCALE));
            atomicAdd(&hc[bin], 1);
            atomicAdd(&hs[bin], v);
            if (pos) {
                np_acc++;
                pc_acc += softplus_(-dd);  // lse - c.y
                int t = 15 - (int)(pkey[i] & 15u);
                float tx0 = tr[t][0], ty0 = tr[t][1], tx1 = tr[t][2], ty1 = tr[t][3];
                float gcx = ((tx0 + tx1) * 0.5f - pr[i].x) / (0.1f * pr[i].z);
                float gcy = ((ty0 + ty1) * 0.5f - pr[i].y) / (0.1f * pr[i].w);
                float gw = __logf((tx1 - tx0) / pr[i].z) * 5.0f;
                float gh = __logf((ty1 - ty0) / pr[i].w) * 5.0f;
                float4 ld = ((const float4*)loc)[bp];
                float d0 = fabsf(ld.x - gcx), d1 = fabsf(ld.y - gcy);
                float d2 = fabsf(ld.z - gw),  d3 = fabsf(ld.w - gh);
                ll_acc += (d0 < 1.0f) ? 0.5f * d0 * d0 : d0 - 0.5f;
                ll_acc += (d1 < 1.0f) ? 0.5f * d1 * d1 : d1 - 0.5f;
                ll_acc += (d2 < 1.0f) ? 0.5f * d2 * d2 : d2 - 0.5f;
                ll_acc += (d3 < 1.0f) ? 0.5f * d3 * d3 : d3 - 0.5f;
            }
        }
    }

    // per-wave reductions
    const int wave = tid >> 6, lane = tid & 63;
#pragma unroll
    for (int t = 0; t < NT_; t++) {
        unsigned k = tkey[t], m = k;
        for (int off = 32; off > 0; off >>= 1) {
            unsigned o = __shfl_down(m, off, 64);
            m = (o > m) ? o : m;
        }
        m = __shfl(m, 0, 64);
        unsigned long long ball = __ballot(k == m);
        if (lane == 0) {
            int l = __ffsll((long long)ball) - 1;  // lowest lane = smallest p (same ci)
            int ci = 15 - (int)(m & 15u);
            int p = bx * (CHUNKS * 1024) + ci * 256 + wave * 64 + l;
            wkey[wave][t] = m;
            wp[wave][t] = (unsigned)p;
        }
    }
    for (int off = 32; off > 0; off >>= 1) {
        ll_acc += __shfl_down(ll_acc, off, 64);
        pc_acc += __shfl_down(pc_acc, off, 64);
        np_acc += __shfl_down(np_acc, off, 64);
    }
    if (lane == 0) { sh_ll[wave] = ll_acc; sh_pc[wave] = pc_acc; sh_np[wave] = np_acc; }
    __syncthreads();

    if (tid < NT_) {
        unsigned bk = wkey[0][tid], bpv = wp[0][tid];
        for (int w = 1; w < 4; w++) {
            unsigned k2 = wkey[w][tid], p2 = wp[w][tid];
            if (k2 > bk || (k2 == bk && p2 < bpv)) { bk = k2; bpv = p2; }
        }
        unsigned long long pk = (((unsigned long long)bk) << 32) | (unsigned)(~bpv);
        bestPart[((size_t)b * NT_ + tid) * NBX + bx] = pk;   // plain store
    }
    if (tid == 0) {
        part_ll[b * NBX + bx] = sh_ll[0] + sh_ll[1] + sh_ll[2] + sh_ll[3];
        part_pc[b * NBX + bx] = sh_pc[0] + sh_pc[1] + sh_pc[2] + sh_pc[3];
        part_np[b * NBX + bx] = sh_np[0] + sh_np[1] + sh_np[2] + sh_np[3];
    }
    // deterministic per-block hist writeback (coalesced)
    int* gc = gcnt + ((size_t)(b * NBX + bx)) * HB;
    float* gs = gsum + ((size_t)(b * NBX + bx)) * HB;
    for (int i = tid; i < HB; i += 256) { gc[i] = hc[i]; gs[i] = hs[i]; }
}

// Kernel 2: per-batch merge + fixup + selection; last block does final reduce.
__global__ void __launch_bounds__(1024) finishK(
    const float* __restrict__ loc, const float* __restrict__ conf,
    const float* __restrict__ priors, const float* __restrict__ targets,
    const int* __restrict__ gcnt, const float* __restrict__ gsum,
    const unsigned long long* __restrict__ bestPart,
    const float* __restrict__ part_ll, const float* __restrict__ part_pc,
    const int* __restrict__ part_np,
    float* __restrict__ final_l, float* __restrict__ final_c, int* __restrict__ final_n,
    unsigned* __restrict__ ticket, float* __restrict__ out)
{
    const int b = blockIdx.x, tid = threadIdx.x;  // 1024 threads
    __shared__ int hc[HB];
    __shared__ float hs[HB];
    __shared__ float tr[NT_][5];
    __shared__ unsigned ps[NT_];
    __shared__ float s_dll, s_dpc;
    __shared__ int s_dnp;
    __shared__ unsigned ccnt[16];
    __shared__ float csm[16];
    __shared__ int s_last;

    if (tid == 0) { s_dll = 0.0f; s_dpc = 0.0f; s_dnp = 0; s_last = 0; }
    if (tid < NT_) {
        const float* tp = targets + ((size_t)b * NT_ + tid) * 5;
        float x0 = tp[0], y0 = tp[1], x1 = tp[2], y1 = tp[3];
        tr[tid][0] = x0; tr[tid][1] = y0; tr[tid][2] = x1; tr[tid][3] = y1;
        tr[tid][4] = (x1 - x0) * (y1 - y0);
    }
    // merge 32 per-block hists: one bin per thread, coalesced over j
    {
        int i = tid;  // HB == 1024
        int c = 0; float s = 0.0f;
#pragma unroll
        for (int j = 0; j < NBX; j++) {
            c += gcnt[((size_t)(b * NBX + j)) * HB + i];
            s += gsum[((size_t)(b * NBX + j)) * HB + i];
        }
        hc[i] = c; hs[i] = s;
    }
    // merge per-truth best priors
    if (tid < NT_) {
        unsigned long long v = bestPart[((size_t)b * NT_ + tid) * NBX];
        for (int j = 1; j < NBX; j++) {
            unsigned long long u = bestPart[((size_t)b * NT_ + tid) * NBX + j];
            if (u > v) v = u;   // equal keys keep first j = smaller prior range
        }
        ps[tid] = ~((unsigned)(v & 0xffffffffULL));
    }
    __syncthreads();

    // fixup (16 threads), adjustments into LDS
    if (tid < NT_) {
        unsigned p = ps[tid];
        bool active = true;
        for (int u = tid + 1; u < NT_; u++)
            if (ps[u] == p) { active = false; break; }  // last-wins dedup
        if (active) {
            float4 prv = ((const float4*)priors)[p];
            float hw = prv.z * 0.5f, hh = prv.w * 0.5f;
            float qx0 = prv.x - hw, qy0 = prv.y - hh;
            float qx1 = prv.x + hw, qy1 = prv.y + hh;
            float areab = (qx1 - qx0) * (qy1 - qy0);
            unsigned pk = 0u;
            for (int tt = 0; tt < NT_; tt++) {
                float iou = iou_fast(tr[tt][0], tr[tt][1], tr[tt][2], tr[tt][3], tr[tt][4],
                                     qx0, qy0, qx1, qy1, areab);
                unsigned cand = ((__float_as_uint(iou) & 0xFFFFFFFCu) << 2)
                              | (unsigned)(15 - tt);
                pk = (cand > pk) ? cand : pk;
            }
            bool pos0 = (pk >= 0xFC000000u);   // identical rule to kernel1
            int t0 = 15 - (int)(pk & 15u);
            size_t bp = (size_t)b * NP_ + p;
            float2 cxy = ((const float2*)conf)[bp];
            float dd = cxy.y - cxy.x;
            float4 ld = ((const float4*)loc)[bp];

            auto sl1_of = [&](int tt) -> float {
                float tx0 = tr[tt][0], ty0 = tr[tt][1], tx1 = tr[tt][2], ty1 = tr[tt][3];
                float gcx = ((tx0 + tx1) * 0.5f - prv.x) / (0.1f * prv.z);
                float gcy = ((ty0 + ty1) * 0.5f - prv.y) / (0.1f * prv.w);
                float gw = __logf((tx1 - tx0) / prv.z) * 5.0f;
                float gh = __logf((ty1 - ty0) / prv.w) * 5.0f;
                float d0 = fabsf(ld.x - gcx), d1 = fabsf(ld.y - gcy);
                float d2 = fabsf(ld.z - gw),  d3 = fabsf(ld.w - gh);
                float s = (d0 < 1.0f) ? 0.5f * d0 * d0 : d0 - 0.5f;
                s += (d1 < 1.0f) ? 0.5f * d1 * d1 : d1 - 0.5f;
                s += (d2 < 1.0f) ? 0.5f * d2 * d2 : d2 - 0.5f;
                s += (d3 < 1.0f) ? 0.5f * d3 * d3 : d3 - 0.5f;
                return s;
            };
            float dll = sl1_of(tid) - (pos0 ? sl1_of(t0) : 0.0f);
            atomicAdd(&s_dll, dll);
            if (!pos0) {
                float v = softplus_(dd);  // identical expr to kernel1's binned value
                int bin = min(HB - 1, (int)(v * HSCALE));
                atomicSub(&hc[bin], 1);
                atomicAdd(&hs[bin], -v);
                atomicAdd(&s_dpc, softplus_(-dd));
                atomicAdd(&s_dnp, 1);
            }
        }
    }
    __syncthreads();

    if (tid < 16) {
        unsigned cacc = 0; float sacc = 0.0f;
        for (int j = 0; j < 64; j++) { cacc += (unsigned)hc[tid * 64 + j]; sacc += hs[tid * 64 + j]; }
        ccnt[tid] = cacc; csm[tid] = sacc;
    }
    __syncthreads();

    if (tid == 0) {
        float sll = s_dll, spc = s_dpc;
        int n = s_dnp;
        for (int j = 0; j < NBX; j++) {
            sll += part_ll[b * NBX + j];
            spc += part_pc[b * NBX + j];
            n += part_np[b * NBX + j];
        }
        int K = 3 * n;
        if (K > NP_ - 1) K = NP_ - 1;
        float tk = 0.0f;
        if (K > 0) {
            unsigned need = (unsigned)K, cum = 0;
            float s = 0.0f;
            int cb = 15;
            for (; cb > 0; --cb) {
                if (cum + ccnt[cb] >= need) break;
                cum += ccnt[cb]; s += csm[cb];
            }
            int bin = cb * 64 + 63;
            for (; bin > cb * 64; --bin) {
                if (cum + (unsigned)hc[bin] >= need) break;
                cum += (unsigned)hc[bin]; s += hs[bin];
            }
            unsigned rem = need - cum;
            int cv = hc[bin];
            float avg = (cv > 0) ? __fdividef(hs[bin], (float)cv) : 0.0f;
            tk = s + (float)rem * avg;
        }
        final_l[b] = sll;
        final_c[b] = spc + tk;
        final_n[b] = n;
        __threadfence();
        unsigned old = atomicAdd(ticket, 1u);
        if (old == NB_ - 1) s_last = 1;
    }
    __syncthreads();

    if (s_last) {
        __threadfence();  // acquire: see all other blocks' final_* stores
        if (tid < 64) {
            float lv = 0.0f, cv = 0.0f;
            int nv = 0;
            if (tid < NB_) { lv = final_l[tid]; cv = final_c[tid]; nv = final_n[tid]; }
            for (int off = 32; off > 0; off >>= 1) {
                lv += __shfl_down(lv, off, 64);
                cv += __shfl_down(cv, off, 64);
                nv += __shfl_down(nv, off, 64);
            }
            if (tid == 0) {
                float fn = (float)nv;
                out[0] = lv / fn;
                out[1] = cv / fn;
            }
        }
    }
}

extern "C" void kernel_launch(void* const* d_in, const int* in_sizes, int n_in,
                              void* d_out, int out_size, void* d_ws, size_t ws_size,
                              hipStream_t stream) {
    const float* loc = (const float*)d_in[0];
    const float* conf = (const float*)d_in[1];
    const float* priors = (const float*)d_in[2];
    const float* targets = (const float*)d_in[3];
    float* out = (float*)d_out;

    char* w = (char*)d_ws;
    int* gcnt = (int*)w;                                   // 32*32*1024*4 = 4 MB
    float* gsum = (float*)(w + (4u << 20));                // 4 MB
    char* acc = w + (8u << 20);
    unsigned long long* bestPart = (unsigned long long*)acc;        // 32*16*32*8 = 128 KB
    float* part_ll = (float*)(acc + (128u << 10));                  // 4 KB
    float* part_pc = (float*)(acc + (128u << 10) + 4096);           // 4 KB
    int* part_np   = (int*)(acc + (128u << 10) + 8192);             // 4 KB
    float* final_l = (float*)(acc + (128u << 10) + 12288);          // 128 B
    float* final_c = (float*)(acc + (128u << 10) + 12416);
    int* final_n   = (int*)(acc + (128u << 10) + 12544);
    unsigned* ticket = (unsigned*)(acc + (128u << 10) + 12672);

    mainK<<<dim3(NBX, NB_), 256, 0, stream>>>(loc, conf, priors, targets,
                                              gcnt, gsum, bestPart,
                                              part_ll, part_pc, part_np, ticket);
    finishK<<<NB_, 1024, 0, stream>>>(loc, conf, priors, targets, gcnt, gsum, bestPart,
                                      part_ll, part_pc, part_np,
                                      final_l, final_c, final_n, ticket, out);
}